// Round 3
// baseline (575.905 us; speedup 1.0000x reference)
//
#include <hip/hip_runtime.h>
#include <hip/hip_cooperative_groups.h>
#include <math.h>

namespace cg = cooperative_groups;

// Problem constants (fixed by reference)
#define LEAVES 2048
#define NN     4095      // 2*LEAVES-1 total nodes
#define MEMD   150
#define IOUD   450
#define IND    300
#define HIDD   50
#define NCLSD  5

#define LB   16          // leaves per block in leaf phase (256 groups total)
#define NB   8           // nodes per block in big-level mode
#define GRID 256
#define BLK  512
#define CH   32          // chunks per side in attention partial
#define RCH  128         // rows per chunk

union __align__(16) SM {
    struct { float xs[IND][LB]; float iou[LB][IOUD]; int tok[LB]; } leaf;       // 48064 B
    struct { int li[NB], ri[NB]; float hbuf[3][MEMD][NB]; float outs[NB][750]; } lvl; // 38464 B
    struct { float hl[MEMD], hr[MEMD], hs[MEMD], outs[750]; } lvlB;
    struct { float lastv[2][MEMD]; } sc;
    struct { float red[8]; } st;
    struct { float pv[RCH]; } ap;
    struct { float ba[2*MEMD], catl[300], catr[300], vl[150], vr[150],
                   feats[300], hid[HIDD], logits[NCLSD]; } fin;
};

__global__ __launch_bounds__(BLK) void k_fused(
    const int* __restrict__ ltok, const int* __restrict__ rtok,
    const int* __restrict__ lidx, const int* __restrict__ ridx,
    const float* __restrict__ emb,
    const float* __restrict__ Wx, const float* __restrict__ bx,
    const float* __restrict__ Wh, const float* __restrict__ bh,
    const float* __restrict__ Wf, const float* __restrict__ bf,
    const float* __restrict__ Wattn, const float* __restrict__ battn,
    const float* __restrict__ Wwh, const float* __restrict__ bwh,
    const float* __restrict__ Wwp, const float* __restrict__ bwp,
    float* __restrict__ C, float* __restrict__ H,
    float* __restrict__ s, float* __restrict__ stats,
    float* __restrict__ part, float* __restrict__ outp)
{
    cg::grid_group gg = cg::this_grid();
    __shared__ SM sm;
    const int t   = threadIdx.x;
    const int bid = blockIdx.x;

    // ================= P0: leaves (256 groups of 16, both trees) ==========
    {
        int tree  = bid >> 7;
        int leaf0 = (bid & 127) * LB;
        const int* toks = tree ? rtok : ltok;
        if (t < LB) sm.leaf.tok[t] = toks[leaf0 + t];
        __syncthreads();
        for (int idx = t; idx < LB * IND; idx += BLK) {
            int m = idx / IND, k = idx - m * IND;
            sm.leaf.xs[k][m] = emb[(size_t)sm.leaf.tok[m] * IND + k];
        }
        __syncthreads();
        if (t < IOUD) {
            float bias = bx[t] + bh[t];
            float acc[LB];
            #pragma unroll
            for (int m = 0; m < LB; ++m) acc[m] = bias;
            for (int k = 0; k < IND; ++k) {
                float w = Wx[k * IOUD + t];
                const float4* r = (const float4*)(&sm.leaf.xs[k][0]);
                float4 a0 = r[0], a1 = r[1], a2 = r[2], a3 = r[3];
                acc[0]  += a0.x * w; acc[1]  += a0.y * w; acc[2]  += a0.z * w; acc[3]  += a0.w * w;
                acc[4]  += a1.x * w; acc[5]  += a1.y * w; acc[6]  += a1.z * w; acc[7]  += a1.w * w;
                acc[8]  += a2.x * w; acc[9]  += a2.y * w; acc[10] += a2.z * w; acc[11] += a2.w * w;
                acc[12] += a3.x * w; acc[13] += a3.y * w; acc[14] += a3.z * w; acc[15] += a3.w * w;
            }
            #pragma unroll
            for (int m = 0; m < LB; ++m) sm.leaf.iou[m][t] = acc[m];
        }
        __syncthreads();
        float* Ct = C + (size_t)tree * NN * MEMD;
        float* Ht = H + (size_t)tree * NN * MEMD;
        for (int idx = t; idx < LB * MEMD; idx += BLK) {
            int m = idx / MEMD, d = idx - m * MEMD;
            float iv = sm.leaf.iou[m][d], ov = sm.leaf.iou[m][d + 150], uv = sm.leaf.iou[m][d + 300];
            float ig = 1.f / (1.f + expf(-iv));
            float og = 1.f / (1.f + expf(-ov));
            float ug = tanhf(uv);
            float c  = ig * ug;
            float h  = og * tanhf(c);
            int node = leaf0 + m;
            Ct[node * MEMD + d] = c;
            Ht[node * MEMD + d] = h;
        }
    }
    gg.sync();

    // ================= P1..P11: tree levels ===============================
    int ebase = 0;
    for (int n = 1024; n >= 1; n >>= 1) {
        int total = 2 * n;
        if (total >= 512) {
            // ---- mode A: NB=8 nodes per block ----
            int gpt = n >> 3;
            if (bid < 2 * gpt) {
                int tree = bid / gpt, grp = bid - tree * gpt;
                int n0 = grp * NB;
                float* Ct = C + (size_t)tree * NN * MEMD;
                float* Ht = H + (size_t)tree * NN * MEMD;
                if (t < NB) {
                    int e = ebase + n0 + t;
                    sm.lvl.li[t] = lidx[e];
                    sm.lvl.ri[t] = ridx[e];
                }
                __syncthreads();
                for (int idx = t; idx < NB * MEMD; idx += BLK) {
                    int m = idx / MEMD, d = idx - m * MEMD;
                    float a = Ht[(size_t)sm.lvl.li[m] * MEMD + d];
                    float b = Ht[(size_t)sm.lvl.ri[m] * MEMD + d];
                    sm.lvl.hbuf[0][d][m] = a;
                    sm.lvl.hbuf[1][d][m] = b;
                    sm.lvl.hbuf[2][d][m] = a + b;
                }
                __syncthreads();
                for (int o = t; o < 750; o += BLK) {
                    int sel, col, ncols; const float* Wm; float bias;
                    if (o < 450)      { sel = 2; col = o;       ncols = IOUD; Wm = Wh; bias = bh[o]; }
                    else if (o < 600) { sel = 0; col = o - 450; ncols = MEMD; Wm = Wf; bias = bf[o - 450]; }
                    else              { sel = 1; col = o - 600; ncols = MEMD; Wm = Wf; bias = bf[o - 600]; }
                    float acc[NB];
                    #pragma unroll
                    for (int m = 0; m < NB; ++m) acc[m] = bias;
                    for (int k = 0; k < MEMD; ++k) {
                        float w = Wm[k * ncols + col];
                        const float4* hp = (const float4*)(&sm.lvl.hbuf[sel][k][0]);
                        float4 h0 = hp[0], h1 = hp[1];
                        acc[0] += h0.x * w; acc[1] += h0.y * w; acc[2] += h0.z * w; acc[3] += h0.w * w;
                        acc[4] += h1.x * w; acc[5] += h1.y * w; acc[6] += h1.z * w; acc[7] += h1.w * w;
                    }
                    #pragma unroll
                    for (int m = 0; m < NB; ++m) sm.lvl.outs[m][o] = acc[m];
                }
                __syncthreads();
                for (int idx = t; idx < NB * MEMD; idx += BLK) {
                    int m = idx / MEMD, d = idx - m * MEMD;
                    float iv  = sm.lvl.outs[m][d], ov = sm.lvl.outs[m][d + 150], uv = sm.lvl.outs[m][d + 300];
                    float flv = sm.lvl.outs[m][d + 450], frv = sm.lvl.outs[m][d + 600];
                    float ig = 1.f / (1.f + expf(-iv));
                    float og = 1.f / (1.f + expf(-ov));
                    float ug = tanhf(uv);
                    float fl = 1.f / (1.f + expf(-flv));
                    float fr = 1.f / (1.f + expf(-frv));
                    float c  = ig * ug + fl * Ct[(size_t)sm.lvl.li[m] * MEMD + d]
                                       + fr * Ct[(size_t)sm.lvl.ri[m] * MEMD + d];
                    float h  = og * tanhf(c);
                    int node = LEAVES + ebase + n0 + m;
                    Ct[node * MEMD + d] = c;
                    Ht[node * MEMD + d] = h;
                }
            }
        } else {
            // ---- mode B: one node per block (total = 2n blocks) ----
            if (bid < total) {
                int tree = bid / n, node = bid - tree * n;
                int e = ebase + node;
                int li = lidx[e], ri = ridx[e];
                float* Ct = C + (size_t)tree * NN * MEMD;
                float* Ht = H + (size_t)tree * NN * MEMD;
                if (t < MEMD) {
                    float a = Ht[(size_t)li * MEMD + t];
                    float b = Ht[(size_t)ri * MEMD + t];
                    sm.lvlB.hl[t] = a;
                    sm.lvlB.hr[t] = b;
                    sm.lvlB.hs[t] = a + b;
                }
                __syncthreads();
                for (int o = t; o < 750; o += BLK) {
                    const float* hv; const float* Wm; int col, ncols; float bias;
                    if (o < 450)      { hv = sm.lvlB.hs; Wm = Wh; col = o;       ncols = IOUD; bias = bh[o]; }
                    else if (o < 600) { hv = sm.lvlB.hl; Wm = Wf; col = o - 450; ncols = MEMD; bias = bf[o - 450]; }
                    else              { hv = sm.lvlB.hr; Wm = Wf; col = o - 600; ncols = MEMD; bias = bf[o - 600]; }
                    float acc = bias;
                    for (int k = 0; k < MEMD; ++k) acc += hv[k] * Wm[k * ncols + col];
                    sm.lvlB.outs[o] = acc;
                }
                __syncthreads();
                if (t < MEMD) {
                    int d = t;
                    float iv  = sm.lvlB.outs[d], ov = sm.lvlB.outs[d + 150], uv = sm.lvlB.outs[d + 300];
                    float flv = sm.lvlB.outs[d + 450], frv = sm.lvlB.outs[d + 600];
                    float ig = 1.f / (1.f + expf(-iv));
                    float og = 1.f / (1.f + expf(-ov));
                    float ug = tanhf(uv);
                    float fl = 1.f / (1.f + expf(-flv));
                    float fr = 1.f / (1.f + expf(-frv));
                    float c  = ig * ug + fl * Ct[(size_t)li * MEMD + d]
                                       + fr * Ct[(size_t)ri * MEMD + d];
                    float h  = og * tanhf(c);
                    int node2 = LEAVES + ebase + node;
                    Ct[node2 * MEMD + d] = c;
                    Ht[node2 * MEMD + d] = h;
                }
            }
        }
        ebase += n;
        gg.sync();
    }

    // ================= P12: score row/col =================================
    {
        const float* Hl = H;
        const float* Hr = H + (size_t)NN * MEMD;
        if (t < MEMD) {
            sm.sc.lastv[0][t] = Hl[(size_t)(NN - 1) * MEMD + t];
            sm.sc.lastv[1][t] = Hr[(size_t)(NN - 1) * MEMD + t];
        }
        __syncthreads();
        int wave = t >> 6, lane = t & 63;
        for (int idx = bid * 8 + wave; idx < 2 * NN; idx += GRID * 8) {
            int side = (idx >= NN) ? 1 : 0;
            int j = idx - side * NN;
            const float* row = (side ? Hl : Hr) + (size_t)j * MEMD;
            const float* lv = sm.sc.lastv[side];
            float acc = 0.f;
            for (int d = lane; d < MEMD; d += 64) acc += lv[d] * row[d];
            #pragma unroll
            for (int off = 32; off; off >>= 1) acc += __shfl_xor(acc, off);
            if (lane == 0) s[side * NN + j] = acc;
        }
    }
    gg.sync();

    // ================= P13: softmax stats (blocks 0,1) ====================
    if (bid < 2) {
        const float* sv = s + bid * NN;
        float mx = -3.4e38f;
        for (int j = t; j < NN; j += BLK) mx = fmaxf(mx, sv[j]);
        #pragma unroll
        for (int off = 32; off; off >>= 1) mx = fmaxf(mx, __shfl_xor(mx, off));
        if ((t & 63) == 0) sm.st.red[t >> 6] = mx;
        __syncthreads();
        float gmx = sm.st.red[0];
        #pragma unroll
        for (int w = 1; w < 8; ++w) gmx = fmaxf(gmx, sm.st.red[w]);
        __syncthreads();
        float se = 0.f;
        for (int j = t; j < NN; j += BLK) se += expf(sv[j] - gmx);
        #pragma unroll
        for (int off = 32; off; off >>= 1) se += __shfl_xor(se, off);
        if ((t & 63) == 0) sm.st.red[t >> 6] = se;
        __syncthreads();
        if (t == 0) {
            float gse = 0.f;
            #pragma unroll
            for (int w = 0; w < 8; ++w) gse += sm.st.red[w];
            stats[bid * 2 + 0] = gmx;
            stats[bid * 2 + 1] = gse;
        }
    }
    gg.sync();

    // ================= P14: attention partial sums ========================
    if (bid < 2 * CH) {
        int side = bid / CH, chunk = bid - side * CH;
        const float* sv  = s + side * NN;
        const float* src = (side == 0) ? (H + (size_t)NN * MEMD) : H;
        float gmx = stats[side * 2];
        int j0 = chunk * RCH;
        int jn = min(NN - j0, RCH);
        for (int tt = t; tt < jn; tt += BLK) sm.ap.pv[tt] = expf(sv[j0 + tt] - gmx);
        __syncthreads();
        if (t < MEMD) {
            float acc = 0.f;
            const float* base = src + (size_t)j0 * MEMD + t;
            for (int j = 0; j < jn; ++j) acc += sm.ap.pv[j] * base[(size_t)j * MEMD];
            part[(size_t)(side * CH + chunk) * MEMD + t] = acc;
        }
    }
    gg.sync();

    // ================= P15: reduce + final readout (block 0) ==============
    if (bid == 0) {
        if (t < 2 * MEMD) {
            int side = t / MEMD, d = t - side * MEMD;
            float acc = 0.f;
            #pragma unroll 4
            for (int c2 = 0; c2 < CH; ++c2) acc += part[(size_t)(side * CH + c2) * MEMD + d];
            sm.fin.ba[t] = acc / stats[side * 2 + 1];
        }
        __syncthreads();
        const float* Hl = H;
        const float* Hr = H + (size_t)NN * MEMD;
        for (int d = t; d < 150; d += BLK) {
            sm.fin.catl[d]       = Hl[(size_t)(NN - 1) * MEMD + d];
            sm.fin.catl[150 + d] = sm.fin.ba[d];
            sm.fin.catr[d]       = Hr[(size_t)(NN - 1) * MEMD + d];
            sm.fin.catr[150 + d] = sm.fin.ba[150 + d];
        }
        __syncthreads();
        for (int o = t; o < 300; o += BLK) {
            int d = (o < 150) ? o : o - 150;
            const float* cat = (o < 150) ? sm.fin.catl : sm.fin.catr;
            float acc = battn[d];
            for (int k = 0; k < 300; ++k) acc += cat[k] * Wattn[k * 150 + d];
            if (o < 150) sm.fin.vl[d] = acc; else sm.fin.vr[d] = acc;
        }
        __syncthreads();
        for (int d = t; d < 150; d += BLK) {
            sm.fin.feats[d]       = sm.fin.vl[d] * sm.fin.vr[d];
            sm.fin.feats[150 + d] = fabsf(sm.fin.vl[d] - sm.fin.vr[d]);
        }
        __syncthreads();
        if (t < HIDD) {
            float acc = bwh[t];
            for (int k = 0; k < 300; ++k) acc += sm.fin.feats[k] * Wwh[k * HIDD + t];
            sm.fin.hid[t] = 1.f / (1.f + expf(-acc));
        }
        __syncthreads();
        if (t < NCLSD) {
            float acc = bwp[t];
            for (int g2 = 0; g2 < HIDD; ++g2) acc += sm.fin.hid[g2] * Wwp[g2 * NCLSD + t];
            sm.fin.logits[t] = acc;
        }
        __syncthreads();
        if (t == 0) {
            float m = sm.fin.logits[0];
            for (int c2 = 1; c2 < NCLSD; ++c2) m = fmaxf(m, sm.fin.logits[c2]);
            float sse = 0.f;
            for (int c2 = 0; c2 < NCLSD; ++c2) sse += expf(sm.fin.logits[c2] - m);
            float lse = m + logf(sse);
            for (int c2 = 0; c2 < NCLSD; ++c2) outp[c2] = sm.fin.logits[c2] - lse;
        }
    }
}

// ---------------------------------------------------------------------------
extern "C" void kernel_launch(void* const* d_in, const int* in_sizes, int n_in,
                              void* d_out, int out_size, void* d_ws, size_t ws_size,
                              hipStream_t stream)
{
    const int*   ltok  = (const int*)d_in[0];
    const int*   rtok  = (const int*)d_in[1];
    const int*   lidx  = (const int*)d_in[2];
    const int*   ridx  = (const int*)d_in[3];
    const float* emb   = (const float*)d_in[4];
    const float* Wx    = (const float*)d_in[5];
    const float* bx    = (const float*)d_in[6];
    const float* Wh    = (const float*)d_in[7];
    const float* bh    = (const float*)d_in[8];
    // d_in[9] (W_fx), d_in[10] (b_fx) unused by the reference
    const float* Wf    = (const float*)d_in[11];
    const float* bf    = (const float*)d_in[12];
    const float* Wattn = (const float*)d_in[13];
    const float* battn = (const float*)d_in[14];
    const float* Wwh   = (const float*)d_in[15];
    const float* bwh   = (const float*)d_in[16];
    const float* Wwp   = (const float*)d_in[17];
    const float* bwp   = (const float*)d_in[18];
    float* out = (float*)d_out;

    float* ws    = (float*)d_ws;
    float* C     = ws;                              // 2*NN*MEMD
    float* H     = C + (size_t)2 * NN * MEMD;       // 2*NN*MEMD
    float* s     = H + (size_t)2 * NN * MEMD;       // 2*NN
    float* stats = s + (size_t)2 * NN;              // 4
    float* part  = stats + 4;                       // 2*CH*MEMD

    void* args[] = {
        (void*)&ltok, (void*)&rtok, (void*)&lidx, (void*)&ridx, (void*)&emb,
        (void*)&Wx, (void*)&bx, (void*)&Wh, (void*)&bh, (void*)&Wf, (void*)&bf,
        (void*)&Wattn, (void*)&battn, (void*)&Wwh, (void*)&bwh, (void*)&Wwp, (void*)&bwp,
        (void*)&C, (void*)&H, (void*)&s, (void*)&stats, (void*)&part, (void*)&out
    };
    hipLaunchCooperativeKernel((const void*)k_fused, dim3(GRID), dim3(BLK),
                               args, 0, stream);
}

// Round 4
// 409.015 us; speedup vs baseline: 1.4080x; 1.4080x over previous
//
#include <hip/hip_runtime.h>
#include <math.h>

// Problem constants (fixed by reference)
#define LEAVES 2048
#define NN     4095      // 2*LEAVES-1 total nodes
#define MEMD   150
#define IOUD   450
#define IND    300
#define STR    152       // padded row stride (float4-aligned) for C/H/HS
#define CT     4096      // rows per tree in C/H
#define HT     2048      // rows per tree in HS (internal-node hsums)

__device__ __forceinline__ float sigf(float x) { return 1.f / (1.f + expf(-x)); }

// ---------------------------------------------------------------------------
// Leaf kernel: 256 blocks x 512 thr, 16 leaves/block.
// x rows read via uniform (scalar-path) loads; weights streamed per-lane.
// Also writes HSUM for the 8 leaf-parents of the block (siblings in-block).
// ---------------------------------------------------------------------------
__global__ __launch_bounds__(512) void k_leaf(
    const int* __restrict__ ltok, const int* __restrict__ rtok,
    const float* __restrict__ emb, const float* __restrict__ Wx,
    const float* __restrict__ bx, const float* __restrict__ bh,
    float* __restrict__ C, float* __restrict__ H, float* __restrict__ HS)
{
    __shared__ float iou[16][IOUD];
    __shared__ float hst[16][MEMD];
    const int bid = blockIdx.x, t = threadIdx.x;
    const int tree = bid >> 7, leaf0 = (bid & 127) << 4;
    const int* toks = tree ? rtok : ltok;

    const float* xr[16];
    #pragma unroll
    for (int m = 0; m < 16; ++m)
        xr[m] = emb + (size_t)toks[leaf0 + m] * IND;

    if (t < IOUD) {
        float b = bx[t] + bh[t];
        float acc[16];
        #pragma unroll
        for (int m = 0; m < 16; ++m) acc[m] = b;
        const float* wp = Wx + t;
        for (int k = 0; k < IND; k += 4) {
            float w0 = wp[(k+0)*IOUD], w1 = wp[(k+1)*IOUD],
                  w2 = wp[(k+2)*IOUD], w3 = wp[(k+3)*IOUD];
            #pragma unroll
            for (int m = 0; m < 16; ++m) {
                float4 x4 = *(const float4*)(xr[m] + k);
                acc[m] = fmaf(x4.x, w0, acc[m]);
                acc[m] = fmaf(x4.y, w1, acc[m]);
                acc[m] = fmaf(x4.z, w2, acc[m]);
                acc[m] = fmaf(x4.w, w3, acc[m]);
            }
        }
        #pragma unroll
        for (int m = 0; m < 16; ++m) iou[m][t] = acc[m];
    }
    __syncthreads();

    float* Ct = C + (size_t)tree * CT * STR;
    float* Ht = H + (size_t)tree * CT * STR;
    for (int idx = t; idx < 16 * MEMD; idx += 512) {
        int m = idx / MEMD, d = idx - m * MEMD;
        float iv = iou[m][d], ov = iou[m][d + 150], uv = iou[m][d + 300];
        float c = sigf(iv) * tanhf(uv);
        float h = sigf(ov) * tanhf(c);
        int node = leaf0 + m;
        Ct[(size_t)node * STR + d] = c;
        Ht[(size_t)node * STR + d] = h;
        hst[m][d] = h;
    }
    __syncthreads();
    float* HSt = HS + (size_t)tree * HT * STR;
    int p0 = leaf0 >> 1;
    for (int idx = t; idx < 8 * MEMD; idx += 512) {
        int p = idx / MEMD, d = idx - p * MEMD;
        HSt[(size_t)(p0 + p) * STR + d] = hst[2*p][d] + hst[2*p+1][d];
    }
}

// ---------------------------------------------------------------------------
// Level kernel: 8 consecutive nodes per block (sibling-pair aligned).
// Gate cols read HSUM rows (uniform/scalar path); f cols read child H rows.
// Writes C,H for the level + HSUM for its parents. No atomics, no LDS GEMM.
// ---------------------------------------------------------------------------
__global__ __launch_bounds__(768) void k_level(
    const int* __restrict__ lidx, const int* __restrict__ ridx,
    const float* __restrict__ Wh, const float* __restrict__ bh,
    const float* __restrict__ Wf, const float* __restrict__ bf,
    const float* __restrict__ Crd, const float* __restrict__ Hrd,
    const float* __restrict__ HSrd,
    float* __restrict__ Cwr, float* __restrict__ Hwr, float* __restrict__ HSwr,
    int ebase, int n)
{
    __shared__ float outs[8][752];
    __shared__ float hst[8][MEMD];
    const int bpt = (n + 7) >> 3;
    const int bid = blockIdx.x, t = threadIdx.x;
    const int tree = bid / bpt, grp = bid - tree * bpt;
    const int n0 = grp << 3;
    const int nm = min(8, n - n0);
    const int e0 = ebase + n0;

    const float* HSt = HSrd + (size_t)tree * HT * STR;
    const float* Ht  = Hrd  + (size_t)tree * CT * STR;
    const float* Ct  = Crd  + (size_t)tree * CT * STR;

    if (t < 750) {
        float acc[8];
        const float* rp[8];
        if (t < 450) {
            #pragma unroll
            for (int m = 0; m < 8; ++m) {
                int mm = (m < nm) ? m : 0;
                rp[m] = HSt + (size_t)(e0 + mm) * STR;
            }
            const float* wp = Wh + t;
            float b = bh[t];
            #pragma unroll
            for (int m = 0; m < 8; ++m) acc[m] = b;
            for (int k = 0; k < 148; k += 4) {
                float w0 = wp[(k+0)*IOUD], w1 = wp[(k+1)*IOUD],
                      w2 = wp[(k+2)*IOUD], w3 = wp[(k+3)*IOUD];
                #pragma unroll
                for (int m = 0; m < 8; ++m) {
                    float4 h4 = *(const float4*)(rp[m] + k);
                    acc[m] = fmaf(h4.x, w0, acc[m]);
                    acc[m] = fmaf(h4.y, w1, acc[m]);
                    acc[m] = fmaf(h4.z, w2, acc[m]);
                    acc[m] = fmaf(h4.w, w3, acc[m]);
                }
            }
            { float w0 = wp[148*IOUD], w1 = wp[149*IOUD];
              #pragma unroll
              for (int m = 0; m < 8; ++m) {
                  float2 h2 = *(const float2*)(rp[m] + 148);
                  acc[m] = fmaf(h2.x, w0, acc[m]);
                  acc[m] = fmaf(h2.y, w1, acc[m]); } }
        } else if (t < 600) {
            int col = t - 450;
            #pragma unroll
            for (int m = 0; m < 8; ++m) {
                int mm = (m < nm) ? m : 0;
                rp[m] = Ht + (size_t)lidx[e0 + mm] * STR;
            }
            const float* wp = Wf + col;
            float b = bf[col];
            #pragma unroll
            for (int m = 0; m < 8; ++m) acc[m] = b;
            for (int k = 0; k < 148; k += 4) {
                float w0 = wp[(k+0)*MEMD], w1 = wp[(k+1)*MEMD],
                      w2 = wp[(k+2)*MEMD], w3 = wp[(k+3)*MEMD];
                #pragma unroll
                for (int m = 0; m < 8; ++m) {
                    float4 h4 = *(const float4*)(rp[m] + k);
                    acc[m] = fmaf(h4.x, w0, acc[m]);
                    acc[m] = fmaf(h4.y, w1, acc[m]);
                    acc[m] = fmaf(h4.z, w2, acc[m]);
                    acc[m] = fmaf(h4.w, w3, acc[m]);
                }
            }
            { float w0 = wp[148*MEMD], w1 = wp[149*MEMD];
              #pragma unroll
              for (int m = 0; m < 8; ++m) {
                  float2 h2 = *(const float2*)(rp[m] + 148);
                  acc[m] = fmaf(h2.x, w0, acc[m]);
                  acc[m] = fmaf(h2.y, w1, acc[m]); } }
        } else {
            int col = t - 600;
            #pragma unroll
            for (int m = 0; m < 8; ++m) {
                int mm = (m < nm) ? m : 0;
                rp[m] = Ht + (size_t)ridx[e0 + mm] * STR;
            }
            const float* wp = Wf + col;
            float b = bf[col];
            #pragma unroll
            for (int m = 0; m < 8; ++m) acc[m] = b;
            for (int k = 0; k < 148; k += 4) {
                float w0 = wp[(k+0)*MEMD], w1 = wp[(k+1)*MEMD],
                      w2 = wp[(k+2)*MEMD], w3 = wp[(k+3)*MEMD];
                #pragma unroll
                for (int m = 0; m < 8; ++m) {
                    float4 h4 = *(const float4*)(rp[m] + k);
                    acc[m] = fmaf(h4.x, w0, acc[m]);
                    acc[m] = fmaf(h4.y, w1, acc[m]);
                    acc[m] = fmaf(h4.z, w2, acc[m]);
                    acc[m] = fmaf(h4.w, w3, acc[m]);
                }
            }
            { float w0 = wp[148*MEMD], w1 = wp[149*MEMD];
              #pragma unroll
              for (int m = 0; m < 8; ++m) {
                  float2 h2 = *(const float2*)(rp[m] + 148);
                  acc[m] = fmaf(h2.x, w0, acc[m]);
                  acc[m] = fmaf(h2.y, w1, acc[m]); } }
        }
        #pragma unroll
        for (int m = 0; m < 8; ++m) if (m < nm) outs[m][t] = acc[m];
    }
    __syncthreads();

    float* Cwt = Cwr + (size_t)tree * CT * STR;
    float* Hwt = Hwr + (size_t)tree * CT * STR;
    for (int idx = t; idx < nm * MEMD; idx += 768) {
        int m = idx / MEMD, d = idx - m * MEMD;
        int e = e0 + m;
        int li = lidx[e], ri = ridx[e];
        float iv  = outs[m][d], ov = outs[m][d + 150], uv = outs[m][d + 300];
        float flv = outs[m][d + 450], frv = outs[m][d + 600];
        float c = sigf(iv) * tanhf(uv)
                + sigf(flv) * Ct[(size_t)li * STR + d]
                + sigf(frv) * Ct[(size_t)ri * STR + d];
        float h = sigf(ov) * tanhf(c);
        int gnode = LEAVES + e;
        Cwt[(size_t)gnode * STR + d] = c;
        Hwt[(size_t)gnode * STR + d] = h;
        hst[m][d] = h;
    }
    __syncthreads();
    if (n > 1) {
        float* HSwt = HSwr + (size_t)tree * HT * STR;
        int np = nm >> 1;
        int ep0 = ebase + n + (n0 >> 1);
        for (int idx = t; idx < np * MEMD; idx += 768) {
            int p = idx / MEMD, d = idx - p * MEMD;
            HSwt[(size_t)(ep0 + p) * STR + d] = hst[2*p][d] + hst[2*p+1][d];
        }
    }
}

// ---------------------------------------------------------------------------
// Attention: 128 blocks (2 sides x 64 chunks of 64 rows).
// Per block: scores vs last-row, local softmax stats, partial weighted sum.
// ---------------------------------------------------------------------------
__global__ __launch_bounds__(256) void k_attn(
    const float* __restrict__ H, float* __restrict__ cstat, float* __restrict__ part)
{
    __shared__ float lv[MEMD];
    __shared__ float sc[64];
    __shared__ float pv[64];
    const int bid = blockIdx.x, t = threadIdx.x;
    const int side = bid >> 6, chunk = bid & 63;
    const int j0 = chunk << 6;
    const int jn = min(64, NN - j0);
    const float* lastrow = H + ((size_t)side * CT + (NN - 1)) * STR;
    if (t < MEMD) lv[t] = lastrow[t];
    __syncthreads();

    const float* src = H + (size_t)(side ^ 1) * CT * STR + (size_t)j0 * STR;
    const int wave = t >> 6, lane = t & 63;
    for (int r = wave; r < jn; r += 4) {
        const float* row = src + (size_t)r * STR;
        float a = lv[lane] * row[lane] + lv[lane + 64] * row[lane + 64];
        if (lane < 22) a += lv[lane + 128] * row[lane + 128];
        #pragma unroll
        for (int off = 32; off; off >>= 1) a += __shfl_xor(a, off);
        if (lane == 0) sc[r] = a;
    }
    __syncthreads();
    if (wave == 0) {
        float v = (lane < jn) ? sc[lane] : -3.4e38f;
        float m = v;
        #pragma unroll
        for (int off = 32; off; off >>= 1) m = fmaxf(m, __shfl_xor(m, off));
        float e = (lane < jn) ? expf(v - m) : 0.f;
        pv[lane] = e;
        float s = e;
        #pragma unroll
        for (int off = 32; off; off >>= 1) s += __shfl_xor(s, off);
        if (lane == 0) {
            cstat[(side * 64 + chunk) * 2 + 0] = m;
            cstat[(side * 64 + chunk) * 2 + 1] = s;
        }
    }
    __syncthreads();
    if (t < MEMD) {
        float a = 0.f;
        for (int j = 0; j < jn; ++j) a += pv[j] * src[(size_t)j * STR + t];
        part[(size_t)(side * 64 + chunk) * STR + t] = a;
    }
}

// ---------------------------------------------------------------------------
// Final: merge chunk softmaxes, attention vectors, readout, log_softmax.
// ---------------------------------------------------------------------------
__global__ __launch_bounds__(512) void k_final(
    const float* __restrict__ H, const float* __restrict__ cstat,
    const float* __restrict__ part,
    const float* __restrict__ Wattn, const float* __restrict__ battn,
    const float* __restrict__ Wwh, const float* __restrict__ bwh,
    const float* __restrict__ Wwp, const float* __restrict__ bwp,
    float* __restrict__ outp)
{
    __shared__ float scl[2][64];
    __shared__ float gseS[2];
    __shared__ float ba[300], catl[300], catr[300], vl[150], vr[150];
    __shared__ float feats[300], hid[50], logits[5];
    const int t = threadIdx.x, wave = t >> 6, lane = t & 63;

    if (wave < 2) {
        float lm = cstat[(wave * 64 + lane) * 2 + 0];
        float ls = cstat[(wave * 64 + lane) * 2 + 1];
        float m = lm;
        #pragma unroll
        for (int off = 32; off; off >>= 1) m = fmaxf(m, __shfl_xor(m, off));
        float s = expf(lm - m);
        scl[wave][lane] = s;
        float se = ls * s;
        #pragma unroll
        for (int off = 32; off; off >>= 1) se += __shfl_xor(se, off);
        if (lane == 0) gseS[wave] = se;
    }
    __syncthreads();
    if (t < 300) {
        int side = t / MEMD, d = t - side * MEMD;
        float a = 0.f;
        for (int c = 0; c < 64; ++c)
            a += part[(size_t)(side * 64 + c) * STR + d] * scl[side][c];
        ba[t] = a / gseS[side];
    }
    __syncthreads();
    const float* Hl_last = H + (size_t)(0 * CT + NN - 1) * STR;
    const float* Hr_last = H + (size_t)(1 * CT + NN - 1) * STR;
    if (t < MEMD) {
        catl[t] = Hl_last[t]; catl[150 + t] = ba[t];
        catr[t] = Hr_last[t]; catr[150 + t] = ba[150 + t];
    }
    __syncthreads();
    if (t < 300) {
        int d = (t < 150) ? t : t - 150;
        const float* cat = (t < 150) ? catl : catr;
        float a = battn[d];
        for (int k = 0; k < 300; ++k) a = fmaf(cat[k], Wattn[k * 150 + d], a);
        if (t < 150) vl[d] = a; else vr[d] = a;
    }
    __syncthreads();
    if (t < MEMD) {
        feats[t] = vl[t] * vr[t];
        feats[150 + t] = fabsf(vl[t] - vr[t]);
    }
    __syncthreads();
    if (t < 50) {
        float a = bwh[t];
        for (int k = 0; k < 300; ++k) a = fmaf(feats[k], Wwh[k * 50 + t], a);
        hid[t] = sigf(a);
    }
    __syncthreads();
    if (t < 5) {
        float a = bwp[t];
        for (int g = 0; g < 50; ++g) a = fmaf(hid[g], Wwp[g * 5 + t], a);
        logits[t] = a;
    }
    __syncthreads();
    if (t == 0) {
        float m = logits[0];
        for (int c = 1; c < 5; ++c) m = fmaxf(m, logits[c]);
        float s = 0.f;
        for (int c = 0; c < 5; ++c) s += expf(logits[c] - m);
        float lse = m + logf(s);
        for (int c = 0; c < 5; ++c) outp[c] = logits[c] - lse;
    }
}

// ---------------------------------------------------------------------------
extern "C" void kernel_launch(void* const* d_in, const int* in_sizes, int n_in,
                              void* d_out, int out_size, void* d_ws, size_t ws_size,
                              hipStream_t stream)
{
    const int*   ltok  = (const int*)d_in[0];
    const int*   rtok  = (const int*)d_in[1];
    const int*   lidx  = (const int*)d_in[2];
    const int*   ridx  = (const int*)d_in[3];
    const float* emb   = (const float*)d_in[4];
    const float* Wx    = (const float*)d_in[5];
    const float* bx    = (const float*)d_in[6];
    const float* Wh    = (const float*)d_in[7];
    const float* bh    = (const float*)d_in[8];
    // d_in[9] (W_fx), d_in[10] (b_fx) unused by the reference
    const float* Wf    = (const float*)d_in[11];
    const float* bf    = (const float*)d_in[12];
    const float* Wattn = (const float*)d_in[13];
    const float* battn = (const float*)d_in[14];
    const float* Wwh   = (const float*)d_in[15];
    const float* bwh   = (const float*)d_in[16];
    const float* Wwp   = (const float*)d_in[17];
    const float* bwp   = (const float*)d_in[18];
    float* out = (float*)d_out;

    float* ws   = (float*)d_ws;
    float* C    = ws;                               // 2*CT*STR
    float* H    = C + (size_t)2 * CT * STR;         // 2*CT*STR
    float* HS   = H + (size_t)2 * CT * STR;         // 2*HT*STR
    float* cs   = HS + (size_t)2 * HT * STR;        // 256
    float* part = cs + 256;                         // 128*STR

    k_leaf<<<dim3(256), dim3(512), 0, stream>>>(ltok, rtok, emb, Wx, bx, bh, C, H, HS);

    int ebase = 0;
    for (int n = 1024; n >= 1; n >>= 1) {
        int bpt = (n + 7) >> 3;
        k_level<<<dim3(2 * bpt), dim3(768), 0, stream>>>(
            lidx, ridx, Wh, bh, Wf, bf, C, H, HS, C, H, HS, ebase, n);
        ebase += n;
    }

    k_attn<<<dim3(128), dim3(256), 0, stream>>>(H, cs, part);
    k_final<<<dim3(1), dim3(512), 0, stream>>>(H, cs, part, Wattn, battn,
                                               Wwh, bwh, Wwp, bwp, out);
}

// Round 5
// 253.172 us; speedup vs baseline: 2.2748x; 1.6156x over previous
//
#include <hip/hip_runtime.h>
#include <math.h>

// Problem constants (fixed by reference)
#define LEAVES 2048
#define NN     4095      // 2*LEAVES-1 total nodes
#define MEMD   150
#define IOUD   450
#define IND    300
#define STR    152       // padded row stride for C/H
#define CT     4096      // rows per tree in C/H

__device__ __forceinline__ float sigf(float x) { return 1.f / (1.f + expf(-x)); }

// ---------------------------------------------------------------------------
// Leaf kernel: 256 blocks x 320 thr, 16 leaves/block.
// Thread (d, half) computes i,o,u for dim d of 8 leaves (gate-fused),
// x broadcast from LDS via ds_read_b128, then writes C,H directly.
// ---------------------------------------------------------------------------
__global__ __launch_bounds__(320) void k_leaf(
    const int* __restrict__ ltok, const int* __restrict__ rtok,
    const float* __restrict__ emb, const float* __restrict__ Wx,
    const float* __restrict__ bx, const float* __restrict__ bh,
    float* __restrict__ C, float* __restrict__ H)
{
    __shared__ float xs[IND][16];     // [k][leaf]
    __shared__ int   tok[16];
    const int bid = blockIdx.x, t = threadIdx.x;
    const int tree = bid >> 7, leaf0 = (bid & 127) << 4;
    const int* toks = tree ? rtok : ltok;

    if (t < 16) tok[t] = toks[leaf0 + t];
    __syncthreads();

    // stage 16 embedding rows (float4 global reads, k-major LDS layout)
    for (int ch = t; ch < 16 * 75; ch += 320) {
        int m = ch & 15, q = ch >> 4;          // q < 75
        float4 v = *(const float4*)(emb + (size_t)tok[m] * IND + 4 * q);
        xs[4*q+0][m] = v.x; xs[4*q+1][m] = v.y;
        xs[4*q+2][m] = v.z; xs[4*q+3][m] = v.w;
    }
    __syncthreads();

    if (t < 300) {
        const int hf = (t >= 150) ? 1 : 0;
        const int d  = t - hf * 150;
        const int m0 = hf * 8;
        float ai[8], ao[8], au[8];
        const float bi = bx[d]       + bh[d];
        const float bo = bx[d + 150] + bh[d + 150];
        const float bu = bx[d + 300] + bh[d + 300];
        #pragma unroll
        for (int m = 0; m < 8; ++m) { ai[m] = bi; ao[m] = bo; au[m] = bu; }
        const float* wp = Wx + d;
        for (int k = 0; k < IND; ++k) {
            float wi = wp[k * IOUD];
            float wo = wp[k * IOUD + 150];
            float wu = wp[k * IOUD + 300];
            const float4* xp = (const float4*)(&xs[k][m0]);
            float4 x0 = xp[0], x1 = xp[1];
            float xv[8] = {x0.x, x0.y, x0.z, x0.w, x1.x, x1.y, x1.z, x1.w};
            #pragma unroll
            for (int m = 0; m < 8; ++m) {
                ai[m] = fmaf(xv[m], wi, ai[m]);
                ao[m] = fmaf(xv[m], wo, ao[m]);
                au[m] = fmaf(xv[m], wu, au[m]);
            }
        }
        float* Ct = C + (size_t)tree * CT * STR;
        float* Ht = H + (size_t)tree * CT * STR;
        #pragma unroll
        for (int m = 0; m < 8; ++m) {
            float c = sigf(ai[m]) * tanhf(au[m]);
            float h = sigf(ao[m]) * tanhf(c);
            int node = leaf0 + m0 + m;
            Ct[(size_t)node * STR + d] = c;
            Ht[(size_t)node * STR + d] = h;
        }
    }
}

// ---------------------------------------------------------------------------
// Level kernel: 8 nodes/block, 320 thr. Thread (d, half) computes all five
// gate pre-activations for dim d of 4 nodes. hsum & hl staged in LDS
// (k-major, b128 broadcast); fr recovered as (hsum.Wf) - (hl.Wf).
// ---------------------------------------------------------------------------
__global__ __launch_bounds__(320) void k_level(
    const int* __restrict__ lidx, const int* __restrict__ ridx,
    const float* __restrict__ Wh, const float* __restrict__ bh,
    const float* __restrict__ Wf, const float* __restrict__ bf,
    float* __restrict__ C, float* __restrict__ H,
    int ebase, int n)
{
    __shared__ float hsum[MEMD][8];   // [k][node]
    __shared__ float hlft[MEMD][8];
    __shared__ int   li[8], ri[8];
    const int bpt = (n + 7) >> 3;
    const int bid = blockIdx.x, t = threadIdx.x;
    const int tree = bid / bpt, grp = bid - tree * bpt;
    const int n0 = grp << 3;
    const int nm = min(8, n - n0);
    const int e0 = ebase + n0;

    float* Ct = C + (size_t)tree * CT * STR;
    float* Ht = H + (size_t)tree * CT * STR;

    if (t < 8) {
        int e = e0 + ((t < nm) ? t : 0);
        li[t] = lidx[e];
        ri[t] = ridx[e];
    }
    __syncthreads();

    // stage hl and hl+hr (global coalesced reads along d)
    for (int idx = t; idx < 8 * MEMD; idx += 320) {
        int m = idx / MEMD, d2 = idx - m * MEMD;
        float a = Ht[(size_t)li[m] * STR + d2];
        float b = Ht[(size_t)ri[m] * STR + d2];
        hlft[d2][m] = a;
        hsum[d2][m] = a + b;
    }
    __syncthreads();

    if (t < 300) {
        const int hf = (t >= 150) ? 1 : 0;
        const int d  = t - hf * 150;
        const int m0 = hf * 4;
        float a_i[4], a_o[4], a_u[4], a_fl[4], a_fs[4];
        const float bi = bh[d], bo = bh[d + 150], bu = bh[d + 300];
        const float bfv = bf[d];
        #pragma unroll
        for (int j = 0; j < 4; ++j) {
            a_i[j] = bi; a_o[j] = bo; a_u[j] = bu;
            a_fl[j] = bfv; a_fs[j] = 2.f * bfv;
        }
        const float* whp = Wh + d;
        const float* wfp = Wf + d;
        for (int k = 0; k < MEMD; ++k) {
            float wi = whp[k * IOUD];
            float wo = whp[k * IOUD + 150];
            float wu = whp[k * IOUD + 300];
            float wf = wfp[k * MEMD];
            float4 hs4 = *(const float4*)(&hsum[k][m0]);
            float4 hl4 = *(const float4*)(&hlft[k][m0]);
            float hsv[4] = {hs4.x, hs4.y, hs4.z, hs4.w};
            float hlv[4] = {hl4.x, hl4.y, hl4.z, hl4.w};
            #pragma unroll
            for (int j = 0; j < 4; ++j) {
                a_i[j]  = fmaf(hsv[j], wi, a_i[j]);
                a_o[j]  = fmaf(hsv[j], wo, a_o[j]);
                a_u[j]  = fmaf(hsv[j], wu, a_u[j]);
                a_fs[j] = fmaf(hsv[j], wf, a_fs[j]);
                a_fl[j] = fmaf(hlv[j], wf, a_fl[j]);
            }
        }
        #pragma unroll
        for (int j = 0; j < 4; ++j) {
            int m = m0 + j;
            if (m < nm) {
                float flv = a_fl[j];
                float frv = a_fs[j] - a_fl[j];
                float c = sigf(a_i[j]) * tanhf(a_u[j])
                        + sigf(flv) * Ct[(size_t)li[m] * STR + d]
                        + sigf(frv) * Ct[(size_t)ri[m] * STR + d];
                float h = sigf(a_o[j]) * tanhf(c);
                int node = LEAVES + e0 + m;
                Ct[(size_t)node * STR + d] = c;
                Ht[(size_t)node * STR + d] = h;
            }
        }
    }
}

// ---------------------------------------------------------------------------
// Attention: 128 blocks (2 sides x 64 chunks of 64 rows).
// Per block: scores vs last-row, local softmax stats, partial weighted sum.
// ---------------------------------------------------------------------------
__global__ __launch_bounds__(256) void k_attn(
    const float* __restrict__ H, float* __restrict__ cstat, float* __restrict__ part)
{
    __shared__ float lv[MEMD];
    __shared__ float sc[64];
    __shared__ float pv[64];
    const int bid = blockIdx.x, t = threadIdx.x;
    const int side = bid >> 6, chunk = bid & 63;
    const int j0 = chunk << 6;
    const int jn = min(64, NN - j0);
    const float* lastrow = H + ((size_t)side * CT + (NN - 1)) * STR;
    if (t < MEMD) lv[t] = lastrow[t];
    __syncthreads();

    const float* src = H + (size_t)(side ^ 1) * CT * STR + (size_t)j0 * STR;
    const int wave = t >> 6, lane = t & 63;
    for (int r = wave; r < jn; r += 4) {
        const float* row = src + (size_t)r * STR;
        float a = lv[lane] * row[lane] + lv[lane + 64] * row[lane + 64];
        if (lane < 22) a += lv[lane + 128] * row[lane + 128];
        #pragma unroll
        for (int off = 32; off; off >>= 1) a += __shfl_xor(a, off);
        if (lane == 0) sc[r] = a;
    }
    __syncthreads();
    if (wave == 0) {
        float v = (lane < jn) ? sc[lane] : -3.4e38f;
        float m = v;
        #pragma unroll
        for (int off = 32; off; off >>= 1) m = fmaxf(m, __shfl_xor(m, off));
        float e = (lane < jn) ? expf(v - m) : 0.f;
        pv[lane] = e;
        float s = e;
        #pragma unroll
        for (int off = 32; off; off >>= 1) s += __shfl_xor(s, off);
        if (lane == 0) {
            cstat[(side * 64 + chunk) * 2 + 0] = m;
            cstat[(side * 64 + chunk) * 2 + 1] = s;
        }
    }
    __syncthreads();
    if (t < MEMD) {
        float a = 0.f;
        for (int j = 0; j < jn; ++j) a += pv[j] * src[(size_t)j * STR + t];
        part[(size_t)(side * 64 + chunk) * STR + t] = a;
    }
}

// ---------------------------------------------------------------------------
// Final: merge chunk softmaxes, attention vectors, readout, log_softmax.
// ---------------------------------------------------------------------------
__global__ __launch_bounds__(512) void k_final(
    const float* __restrict__ H, const float* __restrict__ cstat,
    const float* __restrict__ part,
    const float* __restrict__ Wattn, const float* __restrict__ battn,
    const float* __restrict__ Wwh, const float* __restrict__ bwh,
    const float* __restrict__ Wwp, const float* __restrict__ bwp,
    float* __restrict__ outp)
{
    __shared__ float scl[2][64];
    __shared__ float gseS[2];
    __shared__ float ba[300], catl[300], catr[300], vl[150], vr[150];
    __shared__ float feats[300], hid[50], logits[5];
    const int t = threadIdx.x, wave = t >> 6, lane = t & 63;

    if (wave < 2) {
        float lm = cstat[(wave * 64 + lane) * 2 + 0];
        float ls = cstat[(wave * 64 + lane) * 2 + 1];
        float m = lm;
        #pragma unroll
        for (int off = 32; off; off >>= 1) m = fmaxf(m, __shfl_xor(m, off));
        float s = expf(lm - m);
        scl[wave][lane] = s;
        float se = ls * s;
        #pragma unroll
        for (int off = 32; off; off >>= 1) se += __shfl_xor(se, off);
        if (lane == 0) gseS[wave] = se;
    }
    __syncthreads();
    if (t < 300) {
        int side = t / MEMD, d = t - side * MEMD;
        float a = 0.f;
        for (int c = 0; c < 64; ++c)
            a += part[(size_t)(side * 64 + c) * STR + d] * scl[side][c];
        ba[t] = a / gseS[side];
    }
    __syncthreads();
    const float* Hl_last = H + (size_t)(0 * CT + NN - 1) * STR;
    const float* Hr_last = H + (size_t)(1 * CT + NN - 1) * STR;
    if (t < MEMD) {
        catl[t] = Hl_last[t]; catl[150 + t] = ba[t];
        catr[t] = Hr_last[t]; catr[150 + t] = ba[150 + t];
    }
    __syncthreads();
    if (t < 300) {
        int d = (t < 150) ? t : t - 150;
        const float* cat = (t < 150) ? catl : catr;
        float a = battn[d];
        for (int k = 0; k < 300; ++k) a = fmaf(cat[k], Wattn[k * 150 + d], a);
        if (t < 150) vl[d] = a; else vr[d] = a;
    }
    __syncthreads();
    if (t < MEMD) {
        feats[t] = vl[t] * vr[t];
        feats[150 + t] = fabsf(vl[t] - vr[t]);
    }
    __syncthreads();
    if (t < 50) {
        float a = bwh[t];
        for (int k = 0; k < 300; ++k) a = fmaf(feats[k], Wwh[k * 50 + t], a);
        hid[t] = sigf(a);
    }
    __syncthreads();
    if (t < 5) {
        float a = bwp[t];
        for (int g = 0; g < 50; ++g) a = fmaf(hid[g], Wwp[g * 5 + t], a);
        logits[t] = a;
    }
    __syncthreads();
    if (t == 0) {
        float m = logits[0];
        for (int c = 1; c < 5; ++c) m = fmaxf(m, logits[c]);
        float s = 0.f;
        for (int c = 0; c < 5; ++c) s += expf(logits[c] - m);
        float lse = m + logf(s);
        for (int c = 0; c < 5; ++c) outp[c] = logits[c] - lse;
    }
}

// ---------------------------------------------------------------------------
extern "C" void kernel_launch(void* const* d_in, const int* in_sizes, int n_in,
                              void* d_out, int out_size, void* d_ws, size_t ws_size,
                              hipStream_t stream)
{
    const int*   ltok  = (const int*)d_in[0];
    const int*   rtok  = (const int*)d_in[1];
    const int*   lidx  = (const int*)d_in[2];
    const int*   ridx  = (const int*)d_in[3];
    const float* emb   = (const float*)d_in[4];
    const float* Wx    = (const float*)d_in[5];
    const float* bx    = (const float*)d_in[6];
    const float* Wh    = (const float*)d_in[7];
    const float* bh    = (const float*)d_in[8];
    // d_in[9] (W_fx), d_in[10] (b_fx) unused by the reference
    const float* Wf    = (const float*)d_in[11];
    const float* bf    = (const float*)d_in[12];
    const float* Wattn = (const float*)d_in[13];
    const float* battn = (const float*)d_in[14];
    const float* Wwh   = (const float*)d_in[15];
    const float* bwh   = (const float*)d_in[16];
    const float* Wwp   = (const float*)d_in[17];
    const float* bwp   = (const float*)d_in[18];
    float* out = (float*)d_out;

    float* ws   = (float*)d_ws;
    float* C    = ws;                               // 2*CT*STR
    float* H    = C + (size_t)2 * CT * STR;         // 2*CT*STR
    float* cs   = H + (size_t)2 * CT * STR;         // 256
    float* part = cs + 256;                         // 128*STR

    k_leaf<<<dim3(256), dim3(320), 0, stream>>>(ltok, rtok, emb, Wx, bx, bh, C, H);

    int ebase = 0;
    for (int n = 1024; n >= 1; n >>= 1) {
        int bpt = (n + 7) >> 3;
        k_level<<<dim3(2 * bpt), dim3(320), 0, stream>>>(
            lidx, ridx, Wh, bh, Wf, bf, C, H, ebase, n);
        ebase += n;
    }

    k_attn<<<dim3(128), dim3(256), 0, stream>>>(H, cs, part);
    k_final<<<dim3(1), dim3(512), 0, stream>>>(H, cs, part, Wattn, battn,
                                               Wwh, bwh, Wwp, bwp, out);
}